// Round 4
// baseline (541.176 us; speedup 1.0000x reference)
//
#include <hip/hip_runtime.h>
#include <hip/hip_bf16.h>

// CellSmooth R4:
//  - P and ET stored in MFMA-fragment-blocked layout (1KB = [tile16][kb32][lane][8])
//    so gemm loads A/B fragments as coalesced 1KB global loads: NO LDS, NO
//    barriers in the GEMM K-loop; software-pipelined double-buffered frags.
//    (R3 gemm was 54% MFMA-busy: barrier drain + LDS co-saturation.)
//  - pk: MFMA operands swapped (C rows=j, cols=i) -> lane packs 4 consecutive
//    j -> b64 LDS writes; 1 barrier per 64-j via LDS double buffer; fragment-
//    order coalesced global stores.  exp(q_j) folded multiplicatively.
//  - pk + etrans fused in one kernel (disjoint block ranges) for VALU/BW overlap.
// Fallback to the verified R1 fused kernel if ws_size < ~162 MiB.

typedef __attribute__((ext_vector_type(8))) short bf16x8;
typedef __attribute__((ext_vector_type(4))) float f32x4;
typedef __attribute__((ext_vector_type(16))) float f32x16;

constexpr int N_ = 8192;
constexpr int G_ = 2048;
constexpr int D_ = 64;

__device__ __forceinline__ unsigned short f32_to_bf16(float f) {
  unsigned u = __builtin_bit_cast(unsigned, f);
  u = (u + 0x7FFFu + ((u >> 16) & 1u)) >> 16;  // RTNE
  return (unsigned short)u;
}
__device__ __forceinline__ float bf16_to_f32(unsigned short h) {
  unsigned u = ((unsigned)h) << 16;
  return __builtin_bit_cast(float, u);
}

// --- prep: row norms + packed (norm, exp(quality)) + enc -> bf16 ---
__global__ void prep_kernel(const float* __restrict__ enc,
                            const float* __restrict__ quality,
                            float* __restrict__ norms,
                            float2* __restrict__ nq,
                            unsigned short* __restrict__ encb) {
  int row = blockIdx.x * blockDim.x + threadIdx.x;
  if (row >= N_) return;
  const float* r = enc + (size_t)row * D_;
  float n = 0.f;
#pragma unroll
  for (int k = 0; k < D_; k += 4) {
    float4 v = *(const float4*)(r + k);
    n += v.x * v.x + v.y * v.y + v.z * v.z + v.w * v.w;
    ushort4 h;
    h.x = f32_to_bf16(v.x); h.y = f32_to_bf16(v.y);
    h.z = f32_to_bf16(v.z); h.w = f32_to_bf16(v.w);
    *(ushort4*)(encb + (size_t)row * D_ + k) = h;
  }
  norms[row] = n;
  nq[row] = make_float2(n, __expf(quality[row]));
}

// --- mid: fused pk (blocks 0..1023) + etrans-to-fragment (blocks 1024..5119) ---
// Fragment-block layout: blob[tile16][kb][lane][8] (1 KB per 16rows x 32k).
// Lane (quad,l15) holds M[row=l15][k=quad*8+v], matching the MFMA A/B operand.
__global__ __launch_bounds__(256)
void mid_kernel(const unsigned short* __restrict__ encb,
                const float* __restrict__ norms,
                const float2* __restrict__ nq,        // {norm, exp(q)}
                const float* __restrict__ E,          // expression [N][G] f32
                unsigned short* __restrict__ Pf,      // P frag-blocked [512][256][512]
                unsigned short* __restrict__ Ef,      // ET frag-blocked [128][256][512]
                float* __restrict__ lpart) {          // [8][N]
  __shared__ __align__(16) unsigned short sbuf[2 * 64 * 72];

  const int tid = threadIdx.x;
  const int wave = tid >> 6;
  const int lane = tid & 63;
  const int quad = lane >> 4;
  const int l15 = lane & 15;
  const int bx = blockIdx.x;

  if (bx < 1024) {
    // ---------------- pk part ----------------
    const int jc = bx & 7;
    const int it = bx >> 3;
    const int i0 = it * 64;
    const int jbase = jc * 1024;
    const int irow = i0 + 16 * wave + l15;  // B-operand n=l15 -> column i

    bf16x8 bfrag[2];
#pragma unroll
    for (int ks = 0; ks < 2; ++ks)
      bfrag[ks] = *(const bf16x8*)(encb + (size_t)irow * 64 + ks * 32 + quad * 8);
    const float ni = norms[irow];

    float lsum = 0.f;

    for (int js = 0; js < 16; ++js) {
      const int j0j = jbase + js * 64;
      unsigned short* pbuf = sbuf + (js & 1) * (64 * 72);
#pragma unroll
      for (int jt = 0; jt < 4; ++jt) {
        const int jA = j0j + jt * 16 + l15;  // A-operand row m=l15 -> j
        bf16x8 a0 = *(const bf16x8*)(encb + (size_t)jA * 64 + quad * 8);
        bf16x8 a1 = *(const bf16x8*)(encb + (size_t)jA * 64 + 32 + quad * 8);
        f32x4 s4 = {0.f, 0.f, 0.f, 0.f};
        s4 = __builtin_amdgcn_mfma_f32_16x16x32_bf16(a0, bfrag[0], s4, 0, 0, 0);
        s4 = __builtin_amdgcn_mfma_f32_16x16x32_bf16(a1, bfrag[1], s4, 0, 0, 0);
        // C/D: row (=j-local) = quad*4+r, col (=i) = l15
        const int jrow_base = j0j + jt * 16 + quad * 4;
        ushort4 pk4;
#pragma unroll
        for (int r = 0; r < 4; ++r) {
          const int j = jrow_base + r;
          float2 nq2 = nq[j];
          float d2 = fmaxf(ni + nq2.x - 2.0f * s4[r], 0.f);
          float e = __expf(-sqrtf(d2));
          if (j == irow) e = 1.0f;  // exact diagonal: d=0
          float p = nq2.y * e;      // exp(q_j - d)
          unsigned short pb = f32_to_bf16(p);
          lsum += bf16_to_f32(pb);
          ((unsigned short*)&pk4)[r] = pb;
        }
        *(ushort4*)(&pbuf[(16 * wave + l15) * 72 + jt * 16 + quad * 4]) = pk4;
      }
      __syncthreads();
      // fragment-order store: ib = i-tile16, kb = j/32
#pragma unroll
      for (int kbl = 0; kbl < 2; ++kbl) {
        bf16x8 v = *(const bf16x8*)(&pbuf[(16 * wave + l15) * 72 + kbl * 32 + quad * 8]);
        *(bf16x8*)(Pf + (((size_t)(i0 >> 4) + wave) * 256 + (j0j >> 5) + kbl) * 512 + lane * 8) = v;
      }
      // no second barrier: next js writes the other buffer; js+2 rewrite is
      // fenced by the js+1 barrier which this thread reaches only after reads.
    }
    // row sums: lanes with same l15 (quad varies) hold the same i
    float v = lsum;
    v += __shfl_xor(v, 16);
    v += __shfl_xor(v, 32);
    if (quad == 0) lpart[(size_t)jc * N_ + i0 + 16 * wave + l15] = v;
  } else {
    // ---------------- etrans part: E [N][G] f32 -> Ef frag-blocked ----------------
    const int eb = bx - 1024;            // 0..4095
    const int j0 = (eb & 127) * 64;
    const int g0 = (eb >> 7) * 64;
    unsigned short* t = sbuf;            // [g-local][j-local] 64x72
#pragma unroll
    for (int itr = 0; itr < 4; ++itr) {
      int r = itr * 16 + (tid >> 4);     // j-local
      int c4 = tid & 15;                 // g segment of 4
      float4 v = *(const float4*)(E + (size_t)(j0 + r) * G_ + g0 + c4 * 4);
      t[(c4 * 4 + 0) * 72 + r] = f32_to_bf16(v.x);
      t[(c4 * 4 + 1) * 72 + r] = f32_to_bf16(v.y);
      t[(c4 * 4 + 2) * 72 + r] = f32_to_bf16(v.z);
      t[(c4 * 4 + 3) * 72 + r] = f32_to_bf16(v.w);
    }
    __syncthreads();
#pragma unroll
    for (int kbl = 0; kbl < 2; ++kbl) {
      bf16x8 v = *(const bf16x8*)(&t[(16 * wave + l15) * 72 + kbl * 32 + quad * 8]);
      *(bf16x8*)(Ef + (((size_t)(g0 >> 4) + wave) * 256 + (j0 >> 5) + kbl) * 512 + lane * 8) = v;
    }
  }
}

// --- inv: linv[i] = 1 / sum_c lpart[c][i] ---
__global__ void inv_kernel(const float* __restrict__ lpart,
                           float* __restrict__ linv) {
  int i = blockIdx.x * blockDim.x + threadIdx.x;
  if (i >= N_) return;
  float s = 0.f;
#pragma unroll
  for (int c = 0; c < 8; ++c) s += lpart[(size_t)c * N_ + i];
  linv[i] = 1.0f / s;
}

// --- gemm: out[i][g] = linv[i] * sum_j P[i][j] * ET[g][j] ---
// Barrier-free, LDS-free: 256x128 block tile, wave tile 128x64, fragments
// loaded directly from frag-blocked P/ET as coalesced 1KB wave loads,
// double-buffered one K-step (32) ahead.
__global__ __launch_bounds__(256, 2)
void gemm_kernel(const unsigned short* __restrict__ Pf,
                 const unsigned short* __restrict__ Ef,
                 const float* __restrict__ linv,
                 float* __restrict__ out) {
  const int tid = threadIdx.x;
  const int wave = tid >> 6;
  const int lane = tid & 63;
  const int quad = lane >> 4;
  const int l15 = lane & 15;

  const int g0 = blockIdx.x * 128;
  const int i0 = blockIdx.y * 256;
  const int wrow = (wave >> 1) * 128;
  const int wcol = (wave & 1) * 64;

  const unsigned short* Ab = Pf + ((size_t)((i0 + wrow) >> 4) * 256) * 512 + lane * 8;
  const unsigned short* Bb = Ef + ((size_t)((g0 + wcol) >> 4) * 256) * 512 + lane * 8;

  f32x4 acc[8][4];
#pragma unroll
  for (int a = 0; a < 8; ++a)
#pragma unroll
    for (int b = 0; b < 4; ++b) acc[a][b] = (f32x4){0.f, 0.f, 0.f, 0.f};

  bf16x8 aC[8], bC[4], aN[8], bN[4];
#pragma unroll
  for (int rt = 0; rt < 8; ++rt) aC[rt] = *(const bf16x8*)(Ab + ((size_t)(rt * 256 + 0) << 9));
#pragma unroll
  for (int ct = 0; ct < 4; ++ct) bC[ct] = *(const bf16x8*)(Bb + ((size_t)(ct * 256 + 0) << 9));

  for (int kb = 0; kb < 256; kb += 2) {
    const int k1 = kb + 1;
    const int k2 = (kb + 2) & 255;  // last iter: harmless dummy reload of kb=0
#pragma unroll
    for (int rt = 0; rt < 8; ++rt) aN[rt] = *(const bf16x8*)(Ab + ((size_t)(rt * 256 + k1) << 9));
#pragma unroll
    for (int ct = 0; ct < 4; ++ct) bN[ct] = *(const bf16x8*)(Bb + ((size_t)(ct * 256 + k1) << 9));
#pragma unroll
    for (int rt = 0; rt < 8; ++rt)
#pragma unroll
      for (int ct = 0; ct < 4; ++ct)
        acc[rt][ct] = __builtin_amdgcn_mfma_f32_16x16x32_bf16(aC[rt], bC[ct], acc[rt][ct], 0, 0, 0);
#pragma unroll
    for (int rt = 0; rt < 8; ++rt) aC[rt] = *(const bf16x8*)(Ab + ((size_t)(rt * 256 + k2) << 9));
#pragma unroll
    for (int ct = 0; ct < 4; ++ct) bC[ct] = *(const bf16x8*)(Bb + ((size_t)(ct * 256 + k2) << 9));
#pragma unroll
    for (int rt = 0; rt < 8; ++rt)
#pragma unroll
      for (int ct = 0; ct < 4; ++ct)
        acc[rt][ct] = __builtin_amdgcn_mfma_f32_16x16x32_bf16(aN[rt], bN[ct], acc[rt][ct], 0, 0, 0);
  }

#pragma unroll
  for (int rt = 0; rt < 8; ++rt) {
    float lir[4];
#pragma unroll
    for (int r = 0; r < 4; ++r)
      lir[r] = linv[i0 + wrow + rt * 16 + quad * 4 + r];
#pragma unroll
    for (int ct = 0; ct < 4; ++ct)
#pragma unroll
      for (int r = 0; r < 4; ++r) {
        int row = wrow + rt * 16 + quad * 4 + r;
        int col = wcol + ct * 16 + l15;
        out[(size_t)(i0 + row) * G_ + g0 + col] = acc[rt][ct][r] * lir[r];
      }
  }
}

// ===================== fallback path (ws too small) =====================
__global__ void etrans_rm_kernel(const float* __restrict__ E,
                                 unsigned short* __restrict__ ET) {
  __shared__ __align__(16) unsigned short t[64 * 72];
  int j0 = blockIdx.x * 64;
  int g0 = blockIdx.y * 64;
  int tid = threadIdx.x;
#pragma unroll
  for (int it = 0; it < 4; ++it) {
    int r = it * 16 + (tid >> 4);
    int c4 = tid & 15;
    float4 v = *(const float4*)(E + (size_t)(j0 + r) * G_ + g0 + c4 * 4);
    t[(c4 * 4 + 0) * 72 + r] = f32_to_bf16(v.x);
    t[(c4 * 4 + 1) * 72 + r] = f32_to_bf16(v.y);
    t[(c4 * 4 + 2) * 72 + r] = f32_to_bf16(v.z);
    t[(c4 * 4 + 3) * 72 + r] = f32_to_bf16(v.w);
  }
  __syncthreads();
#pragma unroll
  for (int it = 0; it < 2; ++it) {
    int g = it * 32 + (tid >> 3);
    int ch = tid & 7;
    bf16x8 v = *(const bf16x8*)(&t[g * 72 + ch * 8]);
    *(bf16x8*)(ET + (size_t)(g0 + g) * N_ + j0 + ch * 8) = v;
  }
}

__global__ __launch_bounds__(256, 2)
void fused_kernel(const unsigned short* __restrict__ encb,
                  const float* __restrict__ norms,
                  const float2* __restrict__ nq,       // {norm, exp(q)}
                  const unsigned short* __restrict__ ET,
                  float* __restrict__ out) {
  __shared__ __align__(16) unsigned short p_lds[128 * 72];
  __shared__ __align__(16) unsigned short e_lds[256 * 72];
  __shared__ float linv_lds[128];

  const int tid = threadIdx.x;
  const int wave = tid >> 6;
  const int lane = tid & 63;
  const int quad = lane >> 4;
  const int l15 = lane & 15;
  const int half = lane >> 5;
  const int l31 = lane & 31;

  const int gt = blockIdx.x & 7;
  const int it = blockIdx.x >> 3;
  const int i0 = it * 128;
  const int g0 = gt * 256;

  const int srow = 32 * wave;
  const int wr = wave >> 1, wc = wave & 1;
  const int prow = 64 * wr;
  const int pcol = 128 * wc;

  bf16x8 afrag[2][2];
#pragma unroll
  for (int rt = 0; rt < 2; ++rt)
#pragma unroll
    for (int ks = 0; ks < 2; ++ks)
      afrag[rt][ks] = *(const bf16x8*)(encb +
          (size_t)(i0 + srow + rt * 16 + l15) * 64 + ks * 32 + quad * 8);

  float ni[2][4];
#pragma unroll
  for (int rt = 0; rt < 2; ++rt)
#pragma unroll
    for (int r = 0; r < 4; ++r)
      ni[rt][r] = norms[i0 + srow + rt * 16 + quad * 4 + r];

  float lsum[2][4] = {};
  f32x16 acc[2][4];
#pragma unroll
  for (int a = 0; a < 2; ++a)
#pragma unroll
    for (int b = 0; b < 4; ++b)
#pragma unroll
      for (int e = 0; e < 16; ++e) acc[a][b][e] = 0.f;

  for (int j0j = 0; j0j < N_; j0j += 64) {
#pragma unroll
    for (int s = 0; s < 8; ++s) {
      int g = s * 32 + (tid >> 3);
      int ch = tid & 7;
      bf16x8 v = *(const bf16x8*)(ET + (size_t)(g0 + g) * N_ + j0j + ch * 8);
      *(bf16x8*)(&e_lds[g * 72 + ch * 8]) = v;
    }
#pragma unroll
    for (int jt = 0; jt < 4; ++jt) {
      const int jrow = j0j + jt * 16 + l15;
      bf16x8 b0 = *(const bf16x8*)(encb + (size_t)jrow * 64 + quad * 8);
      bf16x8 b1 = *(const bf16x8*)(encb + (size_t)jrow * 64 + 32 + quad * 8);
      float2 njq = nq[jrow];
#pragma unroll
      for (int rt = 0; rt < 2; ++rt) {
        f32x4 s4 = {0.f, 0.f, 0.f, 0.f};
        s4 = __builtin_amdgcn_mfma_f32_16x16x32_bf16(afrag[rt][0], b0, s4, 0, 0, 0);
        s4 = __builtin_amdgcn_mfma_f32_16x16x32_bf16(afrag[rt][1], b1, s4, 0, 0, 0);
#pragma unroll
        for (int r = 0; r < 4; ++r) {
          int i_loc = srow + rt * 16 + quad * 4 + r;
          float d2 = fmaxf(ni[rt][r] + njq.x - 2.0f * s4[r], 0.f);
          float e = __expf(-sqrtf(d2));
          if (i0 + i_loc == jrow) e = 1.0f;
          float p = njq.y * e;
          unsigned short pb = f32_to_bf16(p);
          lsum[rt][r] += bf16_to_f32(pb);
          p_lds[i_loc * 72 + jt * 16 + l15] = pb;
        }
      }
    }
    __syncthreads();
#pragma unroll
    for (int ks = 0; ks < 4; ++ks) {
      bf16x8 pa0 = *(const bf16x8*)(&p_lds[(prow + l31) * 72 + ks * 16 + half * 8]);
      bf16x8 pa1 = *(const bf16x8*)(&p_lds[(prow + 32 + l31) * 72 + ks * 16 + half * 8]);
#pragma unroll
      for (int ct = 0; ct < 4; ++ct) {
        bf16x8 eb = *(const bf16x8*)(&e_lds[(pcol + ct * 32 + l31) * 72 + ks * 16 + half * 8]);
        acc[0][ct] = __builtin_amdgcn_mfma_f32_32x32x16_bf16(pa0, eb, acc[0][ct], 0, 0, 0);
        acc[1][ct] = __builtin_amdgcn_mfma_f32_32x32x16_bf16(pa1, eb, acc[1][ct], 0, 0, 0);
      }
    }
    __syncthreads();
  }

#pragma unroll
  for (int rt = 0; rt < 2; ++rt)
#pragma unroll
    for (int r = 0; r < 4; ++r) {
      float v = lsum[rt][r];
      v += __shfl_xor(v, 1);
      v += __shfl_xor(v, 2);
      v += __shfl_xor(v, 4);
      v += __shfl_xor(v, 8);
      lsum[rt][r] = v;
    }
  if (l15 == 0) {
#pragma unroll
    for (int rt = 0; rt < 2; ++rt)
#pragma unroll
      for (int r = 0; r < 4; ++r)
        linv_lds[srow + rt * 16 + quad * 4 + r] = 1.0f / lsum[rt][r];
  }
  __syncthreads();

#pragma unroll
  for (int rt2 = 0; rt2 < 2; ++rt2)
#pragma unroll
    for (int ct = 0; ct < 4; ++ct)
#pragma unroll
      for (int e = 0; e < 16; ++e) {
        int row = prow + rt2 * 32 + (e & 3) + 8 * (e >> 2) + 4 * half;
        int col = pcol + ct * 32 + l31;
        out[(size_t)(i0 + row) * G_ + g0 + col] = acc[rt2][ct][e] * linv_lds[row];
      }
}

extern "C" void kernel_launch(void* const* d_in, const int* in_sizes, int n_in,
                              void* d_out, int out_size, void* d_ws, size_t ws_size,
                              hipStream_t stream) {
  const float* expr = (const float*)d_in[0];  // [N][G]
  const float* enc  = (const float*)d_in[1];  // [N][D]
  const float* qual = (const float*)d_in[2];  // [N]
  float* out = (float*)d_out;                 // [N][G] f32

  char* ws = (char*)d_ws;
  const size_t off_norms = 0;
  const size_t off_nq    = 32768;
  const size_t off_lpart = 98304;                     // 8*8192*4 = 256 KB
  const size_t off_linv  = 360448;
  const size_t off_encb  = 393216;                    // 1 MB
  const size_t off_ET    = 1441792;                   // 32 MB (frag-blocked)
  const size_t off_P     = 34996224;                  // 128 MB (frag-blocked)
  const size_t need      = off_P + (size_t)N_ * N_ * 2;  // ~161.4 MiB

  if (ws_size >= need) {
    float* norms         = (float*)(ws + off_norms);
    float2* nqp          = (float2*)(ws + off_nq);
    float* lpart         = (float*)(ws + off_lpart);
    float* linv          = (float*)(ws + off_linv);
    unsigned short* encb = (unsigned short*)(ws + off_encb);
    unsigned short* Ef   = (unsigned short*)(ws + off_ET);
    unsigned short* Pf   = (unsigned short*)(ws + off_P);

    prep_kernel<<<dim3(N_ / 256), dim3(256), 0, stream>>>(enc, qual, norms, nqp, encb);
    mid_kernel<<<dim3(1024 + 4096), dim3(256), 0, stream>>>(encb, norms, nqp, expr, Pf, Ef, lpart);
    inv_kernel<<<dim3(N_ / 256), dim3(256), 0, stream>>>(lpart, linv);
    gemm_kernel<<<dim3(G_ / 128, N_ / 256), dim3(256), 0, stream>>>(Pf, Ef, linv, out);
  } else {
    float* norms         = (float*)ws;
    float2* nqp          = (float2*)(ws + 32768);
    unsigned short* encb = (unsigned short*)(ws + 98304);
    unsigned short* ET   = (unsigned short*)(ws + 1146880);
    prep_kernel<<<dim3(N_ / 256), dim3(256), 0, stream>>>(enc, qual, norms, nqp, encb);
    etrans_rm_kernel<<<dim3(N_ / 64, G_ / 64), dim3(256), 0, stream>>>(expr, ET);
    fused_kernel<<<dim3((N_ / 128) * (G_ / 256)), dim3(256), 0, stream>>>(encb, norms, nqp, ET, out);
  }
}

// Round 5
// 478.917 us; speedup vs baseline: 1.1300x; 1.1300x over previous
//
#include <hip/hip_runtime.h>
#include <hip/hip_bf16.h>

// CellSmooth R5:
//  - Producers (prep/mid) unchanged from R4: P and ET in MFMA-fragment-blocked
//    layout (1KB block = [tile16][kb32][lane][8]).
//  - gemm: LDS staging restored (R4's LDS-free design had zero intra-CU reuse
//    -> 5-10x over L2 budget, 361us).  LDS holds the 1KB fragment blocks
//    directly: ds_read_b128 = perfect sequential sweep (conflict-free, no
//    swizzle VALU); global_load_lds sources are contiguous 1KB chunks.
//    256x256 block, 8 waves of 128x64, BK=32, double-buffered 2x32KB LDS,
//    one-step prefetch, ONE barrier per K-step.
// Fallback to the verified R1 fused kernel if ws_size < ~162 MiB.

typedef __attribute__((ext_vector_type(8))) short bf16x8;
typedef __attribute__((ext_vector_type(4))) float f32x4;
typedef __attribute__((ext_vector_type(16))) float f32x16;

constexpr int N_ = 8192;
constexpr int G_ = 2048;
constexpr int D_ = 64;

__device__ __forceinline__ unsigned short f32_to_bf16(float f) {
  unsigned u = __builtin_bit_cast(unsigned, f);
  u = (u + 0x7FFFu + ((u >> 16) & 1u)) >> 16;  // RTNE
  return (unsigned short)u;
}
__device__ __forceinline__ float bf16_to_f32(unsigned short h) {
  unsigned u = ((unsigned)h) << 16;
  return __builtin_bit_cast(float, u);
}

typedef __attribute__((address_space(1))) const unsigned int glob_u32;
typedef __attribute__((address_space(3))) unsigned int lds_u32;
__device__ __forceinline__ void gload_lds16(const void* g, void* l) {
  __builtin_amdgcn_global_load_lds((glob_u32*)g, (lds_u32*)l, 16, 0, 0);
}

// --- prep: row norms + packed (norm, exp(quality)) + enc -> bf16 ---
__global__ void prep_kernel(const float* __restrict__ enc,
                            const float* __restrict__ quality,
                            float* __restrict__ norms,
                            float2* __restrict__ nq,
                            unsigned short* __restrict__ encb) {
  int row = blockIdx.x * blockDim.x + threadIdx.x;
  if (row >= N_) return;
  const float* r = enc + (size_t)row * D_;
  float n = 0.f;
#pragma unroll
  for (int k = 0; k < D_; k += 4) {
    float4 v = *(const float4*)(r + k);
    n += v.x * v.x + v.y * v.y + v.z * v.z + v.w * v.w;
    ushort4 h;
    h.x = f32_to_bf16(v.x); h.y = f32_to_bf16(v.y);
    h.z = f32_to_bf16(v.z); h.w = f32_to_bf16(v.w);
    *(ushort4*)(encb + (size_t)row * D_ + k) = h;
  }
  norms[row] = n;
  nq[row] = make_float2(n, __expf(quality[row]));
}

// --- mid: fused pk (blocks 0..1023) + etrans-to-fragment (blocks 1024..5119) ---
// Fragment-block layout: blob[tile16][kb][lane][8] (1 KB per 16rows x 32k).
// Lane (quad,l15) holds M[row=l15][k=quad*8+v], matching the MFMA A/B operand.
__global__ __launch_bounds__(256)
void mid_kernel(const unsigned short* __restrict__ encb,
                const float* __restrict__ norms,
                const float2* __restrict__ nq,        // {norm, exp(q)}
                const float* __restrict__ E,          // expression [N][G] f32
                unsigned short* __restrict__ Pf,      // P frag-blocked [512][256][512]
                unsigned short* __restrict__ Ef,      // ET frag-blocked [128][256][512]
                float* __restrict__ lpart) {          // [8][N]
  __shared__ __align__(16) unsigned short sbuf[2 * 64 * 72];

  const int tid = threadIdx.x;
  const int wave = tid >> 6;
  const int lane = tid & 63;
  const int quad = lane >> 4;
  const int l15 = lane & 15;
  const int bx = blockIdx.x;

  if (bx < 1024) {
    // ---------------- pk part ----------------
    const int jc = bx & 7;
    const int it = bx >> 3;
    const int i0 = it * 64;
    const int jbase = jc * 1024;
    const int irow = i0 + 16 * wave + l15;  // B-operand n=l15 -> column i

    bf16x8 bfrag[2];
#pragma unroll
    for (int ks = 0; ks < 2; ++ks)
      bfrag[ks] = *(const bf16x8*)(encb + (size_t)irow * 64 + ks * 32 + quad * 8);
    const float ni = norms[irow];

    float lsum = 0.f;

    for (int js = 0; js < 16; ++js) {
      const int j0j = jbase + js * 64;
      unsigned short* pbuf = sbuf + (js & 1) * (64 * 72);
#pragma unroll
      for (int jt = 0; jt < 4; ++jt) {
        const int jA = j0j + jt * 16 + l15;  // A-operand row m=l15 -> j
        bf16x8 a0 = *(const bf16x8*)(encb + (size_t)jA * 64 + quad * 8);
        bf16x8 a1 = *(const bf16x8*)(encb + (size_t)jA * 64 + 32 + quad * 8);
        f32x4 s4 = {0.f, 0.f, 0.f, 0.f};
        s4 = __builtin_amdgcn_mfma_f32_16x16x32_bf16(a0, bfrag[0], s4, 0, 0, 0);
        s4 = __builtin_amdgcn_mfma_f32_16x16x32_bf16(a1, bfrag[1], s4, 0, 0, 0);
        // C/D: row (=j-local) = quad*4+r, col (=i) = l15
        const int jrow_base = j0j + jt * 16 + quad * 4;
        ushort4 pk4;
#pragma unroll
        for (int r = 0; r < 4; ++r) {
          const int j = jrow_base + r;
          float2 nq2 = nq[j];
          float d2 = fmaxf(ni + nq2.x - 2.0f * s4[r], 0.f);
          float e = __expf(-sqrtf(d2));
          if (j == irow) e = 1.0f;  // exact diagonal: d=0
          float p = nq2.y * e;      // exp(q_j - d)
          unsigned short pb = f32_to_bf16(p);
          lsum += bf16_to_f32(pb);
          ((unsigned short*)&pk4)[r] = pb;
        }
        *(ushort4*)(&pbuf[(16 * wave + l15) * 72 + jt * 16 + quad * 4]) = pk4;
      }
      __syncthreads();
      // fragment-order store: ib = i-tile16, kb = j/32
#pragma unroll
      for (int kbl = 0; kbl < 2; ++kbl) {
        bf16x8 v = *(const bf16x8*)(&pbuf[(16 * wave + l15) * 72 + kbl * 32 + quad * 8]);
        *(bf16x8*)(Pf + (((size_t)(i0 >> 4) + wave) * 256 + (j0j >> 5) + kbl) * 512 + lane * 8) = v;
      }
    }
    // row sums: lanes with same l15 (quad varies) hold the same i
    float v = lsum;
    v += __shfl_xor(v, 16);
    v += __shfl_xor(v, 32);
    if (quad == 0) lpart[(size_t)jc * N_ + i0 + 16 * wave + l15] = v;
  } else {
    // ---------------- etrans part: E [N][G] f32 -> Ef frag-blocked ----------------
    const int eb = bx - 1024;            // 0..4095
    const int j0 = (eb & 127) * 64;
    const int g0 = (eb >> 7) * 64;
    unsigned short* t = sbuf;            // [g-local][j-local] 64x72
#pragma unroll
    for (int itr = 0; itr < 4; ++itr) {
      int r = itr * 16 + (tid >> 4);     // j-local
      int c4 = tid & 15;                 // g segment of 4
      float4 v = *(const float4*)(E + (size_t)(j0 + r) * G_ + g0 + c4 * 4);
      t[(c4 * 4 + 0) * 72 + r] = f32_to_bf16(v.x);
      t[(c4 * 4 + 1) * 72 + r] = f32_to_bf16(v.y);
      t[(c4 * 4 + 2) * 72 + r] = f32_to_bf16(v.z);
      t[(c4 * 4 + 3) * 72 + r] = f32_to_bf16(v.w);
    }
    __syncthreads();
#pragma unroll
    for (int kbl = 0; kbl < 2; ++kbl) {
      bf16x8 v = *(const bf16x8*)(&t[(16 * wave + l15) * 72 + kbl * 32 + quad * 8]);
      *(bf16x8*)(Ef + (((size_t)(g0 >> 4) + wave) * 256 + (j0 >> 5) + kbl) * 512 + lane * 8) = v;
    }
  }
}

// --- inv: linv[i] = 1 / sum_c lpart[c][i] ---
__global__ void inv_kernel(const float* __restrict__ lpart,
                           float* __restrict__ linv) {
  int i = blockIdx.x * blockDim.x + threadIdx.x;
  if (i >= N_) return;
  float s = 0.f;
#pragma unroll
  for (int c = 0; c < 8; ++c) s += lpart[(size_t)c * N_ + i];
  linv[i] = 1.0f / s;
}

// --- gemm: out[i][g] = linv[i] * sum_j P[i][j] * ET[g][j] ---
// 256x256 block, 512 threads (8 waves of 128x64), BK=32, frag-blocked LDS
// double buffer (2 x (16KB A + 16KB B)), one-step prefetch, 1 barrier/step.
__device__ __forceinline__ void gemm_step(
    const unsigned short* __restrict__ Pf, const unsigned short* __restrict__ Ef,
    size_t Abase, size_t Bbase, int kbn, bool pf,
    const unsigned short* curA, const unsigned short* curB,
    unsigned short* nxtA, unsigned short* nxtB,
    int wave, int lane, int wrt, int wct, f32x4 acc[8][4]) {
  if (pf) {
#pragma unroll
    for (int i2 = 0; i2 < 4; ++i2) {
      int c = i2 * 8 + wave;  // wave-uniform chunk id 0..31
      if (c < 16)
        gload_lds16(Pf + Abase + ((size_t)c * 256 + kbn) * 512 + lane * 8,
                    nxtA + c * 512 + lane * 8);
      else
        gload_lds16(Ef + Bbase + ((size_t)(c - 16) * 256 + kbn) * 512 + lane * 8,
                    nxtB + (c - 16) * 512 + lane * 8);
    }
  }
  bf16x8 aF[8], bF[4];
#pragma unroll
  for (int rt = 0; rt < 8; ++rt)
    aF[rt] = *(const bf16x8*)(curA + (wrt * 8 + rt) * 512 + lane * 8);
#pragma unroll
  for (int ct = 0; ct < 4; ++ct)
    bF[ct] = *(const bf16x8*)(curB + (wct * 4 + ct) * 512 + lane * 8);
#pragma unroll
  for (int rt = 0; rt < 8; ++rt)
#pragma unroll
    for (int ct = 0; ct < 4; ++ct)
      acc[rt][ct] = __builtin_amdgcn_mfma_f32_16x16x32_bf16(aF[rt], bF[ct], acc[rt][ct], 0, 0, 0);
  __syncthreads();
}

__global__ __launch_bounds__(512, 2)
void gemm_kernel(const unsigned short* __restrict__ Pf,
                 const unsigned short* __restrict__ Ef,
                 const float* __restrict__ linv,
                 float* __restrict__ out) {
  __shared__ __align__(16) unsigned short sA[2][16 * 512];  // 2 x 16 KB
  __shared__ __align__(16) unsigned short sB[2][16 * 512];  // 2 x 16 KB

  const int tid = threadIdx.x;
  const int wave = tid >> 6;        // 0..7
  const int lane = tid & 63;
  const int quad = lane >> 4;
  const int l15 = lane & 15;

  const int g0 = blockIdx.x * 256;
  const int i0 = blockIdx.y * 256;
  const int wrt = wave >> 2;        // row group (128 rows each)
  const int wct = wave & 3;         // col group (64 cols each)

  const size_t Abase = (size_t)(i0 >> 4) * 256 * 512;  // ushort offset
  const size_t Bbase = (size_t)(g0 >> 4) * 256 * 512;

  f32x4 acc[8][4];
#pragma unroll
  for (int a = 0; a < 8; ++a)
#pragma unroll
    for (int b = 0; b < 4; ++b) acc[a][b] = (f32x4){0.f, 0.f, 0.f, 0.f};

  // stage step 0 into buffer 0
#pragma unroll
  for (int i2 = 0; i2 < 4; ++i2) {
    int c = i2 * 8 + wave;
    if (c < 16)
      gload_lds16(Pf + Abase + ((size_t)c * 256 + 0) * 512 + lane * 8,
                  &sA[0][c * 512 + lane * 8]);
    else
      gload_lds16(Ef + Bbase + ((size_t)(c - 16) * 256 + 0) * 512 + lane * 8,
                  &sB[0][(c - 16) * 512 + lane * 8]);
  }
  __syncthreads();

  for (int kb = 0; kb < 256; kb += 2) {
    gemm_step(Pf, Ef, Abase, Bbase, kb + 1, true,
              sA[0], sB[0], sA[1], sB[1], wave, lane, wrt, wct, acc);
    gemm_step(Pf, Ef, Abase, Bbase, kb + 2, kb + 2 < 256,
              sA[1], sB[1], sA[0], sB[0], wave, lane, wrt, wct, acc);
  }

  // epilogue: C/D 16x16 layout row=quad*4+r, col=l15; fold 1/l
#pragma unroll
  for (int rt = 0; rt < 8; ++rt) {
    float lir[4];
#pragma unroll
    for (int r = 0; r < 4; ++r)
      lir[r] = linv[i0 + wrt * 128 + rt * 16 + quad * 4 + r];
#pragma unroll
    for (int ct = 0; ct < 4; ++ct)
#pragma unroll
      for (int r = 0; r < 4; ++r) {
        int row = wrt * 128 + rt * 16 + quad * 4 + r;
        int col = wct * 64 + ct * 16 + l15;
        out[(size_t)(i0 + row) * G_ + g0 + col] = acc[rt][ct][r] * lir[r];
      }
  }
}

// ===================== fallback path (ws too small) =====================
__global__ void etrans_rm_kernel(const float* __restrict__ E,
                                 unsigned short* __restrict__ ET) {
  __shared__ __align__(16) unsigned short t[64 * 72];
  int j0 = blockIdx.x * 64;
  int g0 = blockIdx.y * 64;
  int tid = threadIdx.x;
#pragma unroll
  for (int it = 0; it < 4; ++it) {
    int r = it * 16 + (tid >> 4);
    int c4 = tid & 15;
    float4 v = *(const float4*)(E + (size_t)(j0 + r) * G_ + g0 + c4 * 4);
    t[(c4 * 4 + 0) * 72 + r] = f32_to_bf16(v.x);
    t[(c4 * 4 + 1) * 72 + r] = f32_to_bf16(v.y);
    t[(c4 * 4 + 2) * 72 + r] = f32_to_bf16(v.z);
    t[(c4 * 4 + 3) * 72 + r] = f32_to_bf16(v.w);
  }
  __syncthreads();
#pragma unroll
  for (int it = 0; it < 2; ++it) {
    int g = it * 32 + (tid >> 3);
    int ch = tid & 7;
    bf16x8 v = *(const bf16x8*)(&t[g * 72 + ch * 8]);
    *(bf16x8*)(ET + (size_t)(g0 + g) * N_ + j0 + ch * 8) = v;
  }
}

__global__ __launch_bounds__(256, 2)
void fused_kernel(const unsigned short* __restrict__ encb,
                  const float* __restrict__ norms,
                  const float2* __restrict__ nq,       // {norm, exp(q)}
                  const unsigned short* __restrict__ ET,
                  float* __restrict__ out) {
  __shared__ __align__(16) unsigned short p_lds[128 * 72];
  __shared__ __align__(16) unsigned short e_lds[256 * 72];
  __shared__ float linv_lds[128];

  const int tid = threadIdx.x;
  const int wave = tid >> 6;
  const int lane = tid & 63;
  const int quad = lane >> 4;
  const int l15 = lane & 15;
  const int half = lane >> 5;
  const int l31 = lane & 31;

  const int gt = blockIdx.x & 7;
  const int it = blockIdx.x >> 3;
  const int i0 = it * 128;
  const int g0 = gt * 256;

  const int srow = 32 * wave;
  const int wr = wave >> 1, wc = wave & 1;
  const int prow = 64 * wr;
  const int pcol = 128 * wc;

  bf16x8 afrag[2][2];
#pragma unroll
  for (int rt = 0; rt < 2; ++rt)
#pragma unroll
    for (int ks = 0; ks < 2; ++ks)
      afrag[rt][ks] = *(const bf16x8*)(encb +
          (size_t)(i0 + srow + rt * 16 + l15) * 64 + ks * 32 + quad * 8);

  float ni[2][4];
#pragma unroll
  for (int rt = 0; rt < 2; ++rt)
#pragma unroll
    for (int r = 0; r < 4; ++r)
      ni[rt][r] = norms[i0 + srow + rt * 16 + quad * 4 + r];

  float lsum[2][4] = {};
  f32x16 acc[2][4];
#pragma unroll
  for (int a = 0; a < 2; ++a)
#pragma unroll
    for (int b = 0; b < 4; ++b)
#pragma unroll
      for (int e = 0; e < 16; ++e) acc[a][b][e] = 0.f;

  for (int j0j = 0; j0j < N_; j0j += 64) {
#pragma unroll
    for (int s = 0; s < 8; ++s) {
      int g = s * 32 + (tid >> 3);
      int ch = tid & 7;
      bf16x8 v = *(const bf16x8*)(ET + (size_t)(g0 + g) * N_ + j0j + ch * 8);
      *(bf16x8*)(&e_lds[g * 72 + ch * 8]) = v;
    }
#pragma unroll
    for (int jt = 0; jt < 4; ++jt) {
      const int jrow = j0j + jt * 16 + l15;
      bf16x8 b0 = *(const bf16x8*)(encb + (size_t)jrow * 64 + quad * 8);
      bf16x8 b1 = *(const bf16x8*)(encb + (size_t)jrow * 64 + 32 + quad * 8);
      float2 njq = nq[jrow];
#pragma unroll
      for (int rt = 0; rt < 2; ++rt) {
        f32x4 s4 = {0.f, 0.f, 0.f, 0.f};
        s4 = __builtin_amdgcn_mfma_f32_16x16x32_bf16(afrag[rt][0], b0, s4, 0, 0, 0);
        s4 = __builtin_amdgcn_mfma_f32_16x16x32_bf16(afrag[rt][1], b1, s4, 0, 0, 0);
#pragma unroll
        for (int r = 0; r < 4; ++r) {
          int i_loc = srow + rt * 16 + quad * 4 + r;
          float d2 = fmaxf(ni[rt][r] + njq.x - 2.0f * s4[r], 0.f);
          float e = __expf(-sqrtf(d2));
          if (i0 + i_loc == jrow) e = 1.0f;
          float p = njq.y * e;
          unsigned short pb = f32_to_bf16(p);
          lsum[rt][r] += bf16_to_f32(pb);
          p_lds[i_loc * 72 + jt * 16 + l15] = pb;
        }
      }
    }
    __syncthreads();
#pragma unroll
    for (int ks = 0; ks < 4; ++ks) {
      bf16x8 pa0 = *(const bf16x8*)(&p_lds[(prow + l31) * 72 + ks * 16 + half * 8]);
      bf16x8 pa1 = *(const bf16x8*)(&p_lds[(prow + 32 + l31) * 72 + ks * 16 + half * 8]);
#pragma unroll
      for (int ct = 0; ct < 4; ++ct) {
        bf16x8 eb = *(const bf16x8*)(&e_lds[(pcol + ct * 32 + l31) * 72 + ks * 16 + half * 8]);
        acc[0][ct] = __builtin_amdgcn_mfma_f32_32x32x16_bf16(pa0, eb, acc[0][ct], 0, 0, 0);
        acc[1][ct] = __builtin_amdgcn_mfma_f32_32x32x16_bf16(pa1, eb, acc[1][ct], 0, 0, 0);
      }
    }
    __syncthreads();
  }

#pragma unroll
  for (int rt = 0; rt < 2; ++rt)
#pragma unroll
    for (int r = 0; r < 4; ++r) {
      float v = lsum[rt][r];
      v += __shfl_xor(v, 1);
      v += __shfl_xor(v, 2);
      v += __shfl_xor(v, 4);
      v += __shfl_xor(v, 8);
      lsum[rt][r] = v;
    }
  if (l15 == 0) {
#pragma unroll
    for (int rt = 0; rt < 2; ++rt)
#pragma unroll
      for (int r = 0; r < 4; ++r)
        linv_lds[srow + rt * 16 + quad * 4 + r] = 1.0f / lsum[rt][r];
  }
  __syncthreads();

#pragma unroll
  for (int rt2 = 0; rt2 < 2; ++rt2)
#pragma unroll
    for (int ct = 0; ct < 4; ++ct)
#pragma unroll
      for (int e = 0; e < 16; ++e) {
        int row = prow + rt2 * 32 + (e & 3) + 8 * (e >> 2) + 4 * half;
        int col = pcol + ct * 32 + l31;
        out[(size_t)(i0 + row) * G_ + g0 + col] = acc[rt2][ct][e] * linv_lds[row];
      }
}

extern "C" void kernel_launch(void* const* d_in, const int* in_sizes, int n_in,
                              void* d_out, int out_size, void* d_ws, size_t ws_size,
                              hipStream_t stream) {
  const float* expr = (const float*)d_in[0];  // [N][G]
  const float* enc  = (const float*)d_in[1];  // [N][D]
  const float* qual = (const float*)d_in[2];  // [N]
  float* out = (float*)d_out;                 // [N][G] f32

  char* ws = (char*)d_ws;
  const size_t off_norms = 0;
  const size_t off_nq    = 32768;
  const size_t off_lpart = 98304;                     // 8*8192*4 = 256 KB
  const size_t off_linv  = 360448;
  const size_t off_encb  = 393216;                    // 1 MB
  const size_t off_ET    = 1441792;                   // 32 MB (frag-blocked)
  const size_t off_P     = 34996224;                  // 128 MB (frag-blocked)
  const size_t need      = off_P + (size_t)N_ * N_ * 2;  // ~161.4 MiB

  if (ws_size >= need) {
    float* norms         = (float*)(ws + off_norms);
    float2* nqp          = (float2*)(ws + off_nq);
    float* lpart         = (float*)(ws + off_lpart);
    float* linv          = (float*)(ws + off_linv);
    unsigned short* encb = (unsigned short*)(ws + off_encb);
    unsigned short* Ef   = (unsigned short*)(ws + off_ET);
    unsigned short* Pf   = (unsigned short*)(ws + off_P);

    prep_kernel<<<dim3(N_ / 256), dim3(256), 0, stream>>>(enc, qual, norms, nqp, encb);
    mid_kernel<<<dim3(1024 + 4096), dim3(256), 0, stream>>>(encb, norms, nqp, expr, Pf, Ef, lpart);
    inv_kernel<<<dim3(N_ / 256), dim3(256), 0, stream>>>(lpart, linv);
    gemm_kernel<<<dim3(G_ / 256, N_ / 256), dim3(512), 0, stream>>>(Pf, Ef, linv, out);
  } else {
    float* norms         = (float*)ws;
    float2* nqp          = (float2*)(ws + 32768);
    unsigned short* encb = (unsigned short*)(ws + 98304);
    unsigned short* ET   = (unsigned short*)(ws + 1146880);
    prep_kernel<<<dim3(N_ / 256), dim3(256), 0, stream>>>(enc, qual, norms, nqp, encb);
    etrans_rm_kernel<<<dim3(N_ / 64, G_ / 64), dim3(256), 0, stream>>>(expr, ET);
    fused_kernel<<<dim3((N_ / 128) * (G_ / 256)), dim3(256), 0, stream>>>(encb, norms, nqp, ET, out);
  }
}